// Round 3
// baseline (1200.190 us; speedup 1.0000x reference)
//
#include <hip/hip_runtime.h>
#include <hip/hip_bf16.h>
#include <math.h>

constexpr int BB = 2;
constexpr int NNODE = 256;   // N
constexpr int DD = 256;      // D == E
constexpr int HH = 8;
constexpr int EE = 256;
constexpr int FF = 1024;     // 4*E

typedef __bf16 bf16x8 __attribute__((ext_vector_type(8)));
typedef float f32x4 __attribute__((ext_vector_type(4)));
typedef unsigned int uint4v __attribute__((ext_vector_type(4)));

#define SWZ(x) ((x) ^ (((x) >> 2) & 3))

__device__ __forceinline__ unsigned short f2bf(float f) {
  unsigned u = __builtin_bit_cast(unsigned, f);
  unsigned r = u + 0x7FFFu + ((u >> 16) & 1u);
  return (unsigned short)(r >> 16);
}
__device__ __forceinline__ float bf2f(unsigned short us) {
  return __builtin_bit_cast(float, (unsigned)us << 16);
}
__device__ __forceinline__ bf16x8 ld_frag(const unsigned short* p) {
  uint4v u = *(const uint4v*)p;
  return __builtin_bit_cast(bf16x8, u);
}

// ---------------- generic transpose ----------------
__global__ void transpose_kernel(const float* __restrict__ src, float* __restrict__ dst,
                                 int rows, int cols) {
  int idx = blockIdx.x * blockDim.x + threadIdx.x;
  int n = rows * cols;
  if (idx < n) {
    int r = idx / cols, c = idx - r * cols;
    dst[c * rows + r] = src[idx];
  }
}

// ---------------- pack weights to MFMA B-fragment layout ----------------
__global__ void pack_b_kernel(const float* __restrict__ src, unsigned short* __restrict__ dst,
                              int K, int Nn) {
  int idx = blockIdx.x * 256 + threadIdx.x;
  int NT = Nn >> 4;
  int total = (K >> 5) * NT * 64;
  if (idx >= total) return;
  int lane = idx & 63, ntkt = idx >> 6;
  int nt = ntkt % NT, kt = ntkt / NT;
  int q = lane >> 4, l15 = lane & 15;
  const float* s = src + (size_t)(nt * 16 + l15) * K + kt * 32 + q * 8;
  float4 a = *(const float4*)s;
  float4 b = *(const float4*)(s + 4);
  unsigned short* d = dst + (size_t)idx * 8;
  d[0] = f2bf(a.x); d[1] = f2bf(a.y); d[2] = f2bf(a.z); d[3] = f2bf(a.w);
  d[4] = f2bf(b.x); d[5] = f2bf(b.y); d[6] = f2bf(b.z); d[7] = f2bf(b.w);
}

// ---------------- qkv projection ----------------
__global__ __launch_bounds__(256) void qkv_kernel(
    const float* __restrict__ nodes, const float* __restrict__ conds,
    const float* __restrict__ WqkvT, const float* __restrict__ bqkv,
    float* __restrict__ Q, float* __restrict__ K, float* __restrict__ V)
{
  __shared__ float sX[DD];
  const int row = blockIdx.x;
  const int b = row >> 8;
  const int tid = threadIdx.x;
  sX[tid] = nodes[(size_t)row * DD + tid] + conds[b * DD + tid];
  __syncthreads();
  float aq = bqkv[tid], ak = bqkv[DD + tid], av = bqkv[2 * DD + tid];
  for (int d = 0; d < DD; d += 4) {
    const float4 x = *(const float4*)&sX[d];
    const float* wp = &WqkvT[d * (3 * DD)];
    aq = fmaf(x.x, wp[tid], aq);
    ak = fmaf(x.x, wp[DD + tid], ak);
    av = fmaf(x.x, wp[2 * DD + tid], av);
    aq = fmaf(x.y, wp[768 + tid], aq);
    ak = fmaf(x.y, wp[768 + DD + tid], ak);
    av = fmaf(x.y, wp[768 + 2 * DD + tid], av);
    aq = fmaf(x.z, wp[1536 + tid], aq);
    ak = fmaf(x.z, wp[1536 + DD + tid], ak);
    av = fmaf(x.z, wp[1536 + 2 * DD + tid], av);
    aq = fmaf(x.w, wp[2304 + tid], aq);
    ak = fmaf(x.w, wp[2304 + DD + tid], ak);
    av = fmaf(x.w, wp[2304 + 2 * DD + tid], av);
  }
  Q[(size_t)row * DD + tid] = aq;
  K[(size_t)row * DD + tid] = ak;
  V[(size_t)row * DD + tid] = av;
}

// ---------------- fused MFMA edge kernel, M=64 per block ----------------
// Block: bi = blk>>2, j0 = (blk&3)*64. 256 threads = 4 waves.
// Wave w owns cols [64w, 64w+64) (4 n-tiles); all 4 m-tiles (64 rows).
__global__ __launch_bounds__(256, 2) void edge_mfma_kernel(
    const float* __restrict__ Q, const float* __restrict__ K,
    const float* __restrict__ edges,
    const unsigned short* __restrict__ Weop, const float* __restrict__ beo,
    const float* __restrict__ g1e, const float* __restrict__ b1e,
    const unsigned short* __restrict__ We1p, const float* __restrict__ be1,
    const unsigned short* __restrict__ We2p, const float* __restrict__ be2,
    const float* __restrict__ g2e, const float* __restrict__ b2e,
    float* __restrict__ logits, float* __restrict__ out_edges)
{
  __shared__ unsigned short sAp[4 * 8 * 64 * 8];   // 32 KB: ne5 -> t, A-frag layout (swizzled)
  __shared__ unsigned short sScr[64 * 264];        // 33 KB union: edges residual bf16 -> h1 chunk
  __shared__ float sQ[256];
  __shared__ float sLog[64][8];
  __shared__ float sSum[64][4], sSsq[64][4];
  __shared__ float sMean[64], sRstd[64];

  const int tid = threadIdx.x;
  const int w = tid >> 6;
  const int lane = tid & 63;
  const int q = lane >> 4;
  const int l15 = lane & 15;
  const int lane_sw = SWZ(lane);

  const int blk = blockIdx.x;
  const int bi = blk >> 2;          // b*N + i
  const int b = bi >> 8;
  const int j0 = (blk & 3) * 64;

  // ---- phase 0 ----
  sQ[tid] = Q[(size_t)bi * DD + tid] * 0.0625f;
  float gam1[4], bet1[4], gam2[4], bet2[4], beoc[4], be2c[4];
  #pragma unroll
  for (int ntl = 0; ntl < 4; ++ntl) {
    const int c = w * 64 + ntl * 16 + l15;
    gam1[ntl] = g1e[c]; bet1[ntl] = b1e[c];
    gam2[ntl] = g2e[c]; bet2[ntl] = b2e[c];
    beoc[ntl] = beo[c]; be2c[ntl] = be2[c];
  }
  __syncthreads();

  // ---- phase 1: ne5 = q*k/16 + edges; residual bf16 -> sScr; logits; pack ne5 -> sAp ----
  {
    const int rr = lane >> 2;            // 0..15
    const int m = 16 * w + rr;
    const int db = lane & 3;
    const size_t krow = ((size_t)(b * NNODE + j0 + m)) * DD;
    const size_t erow = ((size_t)bi * NNODE + j0 + m) * DD;
    const int lane2 = db * 16 + rr;
    const int phys = SWZ(lane2);
    #pragma unroll
    for (int it = 0; it < 8; ++it) {
      const int d0 = it * 32 + db * 8;
      const float4 k0 = *(const float4*)&K[krow + d0];
      const float4 k1 = *(const float4*)&K[krow + d0 + 4];
      const float4 e0 = *(const float4*)&edges[erow + d0];
      const float4 e1 = *(const float4*)&edges[erow + d0 + 4];
      const float4 q0 = *(const float4*)&sQ[d0];
      const float4 q1 = *(const float4*)&sQ[d0 + 4];
      float f[8];
      f[0] = fmaf(q0.x, k0.x, e0.x); f[1] = fmaf(q0.y, k0.y, e0.y);
      f[2] = fmaf(q0.z, k0.z, e0.z); f[3] = fmaf(q0.w, k0.w, e0.w);
      f[4] = fmaf(q1.x, k1.x, e1.x); f[5] = fmaf(q1.y, k1.y, e1.y);
      f[6] = fmaf(q1.z, k1.z, e1.z); f[7] = fmaf(q1.w, k1.w, e1.w);
      // edges residual, bf16, row-major stride 264
      uint4v ep;
      ep.x = (unsigned)f2bf(e0.x) | ((unsigned)f2bf(e0.y) << 16);
      ep.y = (unsigned)f2bf(e0.z) | ((unsigned)f2bf(e0.w) << 16);
      ep.z = (unsigned)f2bf(e1.x) | ((unsigned)f2bf(e1.y) << 16);
      ep.w = (unsigned)f2bf(e1.z) | ((unsigned)f2bf(e1.w) << 16);
      *(uint4v*)&sScr[m * 264 + d0] = ep;
      // logits partial: this 32-chunk is head h=it
      float s = f[0] + f[1] + f[2] + f[3] + f[4] + f[5] + f[6] + f[7];
      s += __shfl_xor(s, 1, 64);
      s += __shfl_xor(s, 2, 64);
      if (db == 0) sLog[m][it] = s;
      // pack ne5 bf16 into swizzled A-frag layout (mt = w, kt = it)
      uint4v pk;
      pk.x = (unsigned)f2bf(f[0]) | ((unsigned)f2bf(f[1]) << 16);
      pk.y = (unsigned)f2bf(f[2]) | ((unsigned)f2bf(f[3]) << 16);
      pk.z = (unsigned)f2bf(f[4]) | ((unsigned)f2bf(f[5]) << 16);
      pk.w = (unsigned)f2bf(f[6]) | ((unsigned)f2bf(f[7]) << 16);
      *(uint4v*)&sAp[((w * 8 + it) * 64 + phys) * 8] = pk;
    }
  }
  __syncthreads();

  // logits out: 512 values, 2 per thread
  {
    int idx = tid;
    logits[((size_t)bi * HH + (idx & 7)) * NNODE + j0 + (idx >> 3)] = sLog[idx >> 3][idx & 7];
    idx = tid + 256;
    logits[((size_t)bi * HH + (idx & 7)) * NNODE + j0 + (idx >> 3)] = sLog[idx >> 3][idx & 7];
  }

  // ---- phase 2: GEMM1  C1[64x256] = ne5 @ Weo^T ----
  f32x4 acc1[4][4];
  #pragma unroll
  for (int mt = 0; mt < 4; ++mt)
    #pragma unroll
    for (int ntl = 0; ntl < 4; ++ntl)
      acc1[mt][ntl] = (f32x4){0.f, 0.f, 0.f, 0.f};
  #pragma unroll
  for (int kt = 0; kt < 8; ++kt) {
    bf16x8 a[4];
    #pragma unroll
    for (int mt = 0; mt < 4; ++mt)
      a[mt] = ld_frag(&sAp[((mt * 8 + kt) * 64 + lane_sw) * 8]);
    #pragma unroll
    for (int ntl = 0; ntl < 4; ++ntl) {
      const bf16x8 bfr = ld_frag(&Weop[((size_t)((kt * 16 + 4 * w + ntl) * 64 + lane)) * 8]);
      #pragma unroll
      for (int mt = 0; mt < 4; ++mt)
        acc1[mt][ntl] = __builtin_amdgcn_mfma_f32_16x16x32_bf16(a[mt], bfr, acc1[mt][ntl], 0, 0, 0);
    }
  }

  // ---- phase 3: tpre = relu(C1+beo) + edges; LN1; t -> sAp ----
  float tpre[4][4][4];
  #pragma unroll
  for (int mt = 0; mt < 4; ++mt) {
    #pragma unroll
    for (int r = 0; r < 4; ++r) {
      const int m_ = mt * 16 + q * 4 + r;
      #pragma unroll
      for (int ntl = 0; ntl < 4; ++ntl) {
        const int col = w * 64 + ntl * 16 + l15;
        const float ed = bf2f(sScr[m_ * 264 + col]);
        tpre[mt][ntl][r] = fmaxf(acc1[mt][ntl][r] + beoc[ntl], 0.f) + ed;
      }
    }
  }
  #pragma unroll
  for (int mt = 0; mt < 4; ++mt) {
    #pragma unroll
    for (int r = 0; r < 4; ++r) {
      float s = 0.f, ss = 0.f;
      #pragma unroll
      for (int ntl = 0; ntl < 4; ++ntl) {
        const float v = tpre[mt][ntl][r];
        s += v; ss += v * v;
      }
      #pragma unroll
      for (int off = 1; off < 16; off <<= 1) {
        s += __shfl_xor(s, off, 64);
        ss += __shfl_xor(ss, off, 64);
      }
      if (l15 == 0) {
        const int m_ = mt * 16 + q * 4 + r;
        sSum[m_][w] = s; sSsq[m_][w] = ss;
      }
    }
  }
  __syncthreads();
  if (tid < 64) {
    const float S = sSum[tid][0] + sSum[tid][1] + sSum[tid][2] + sSum[tid][3];
    const float SS = sSsq[tid][0] + sSsq[tid][1] + sSsq[tid][2] + sSsq[tid][3];
    const float mn = S * (1.f / 256.f);
    sMean[tid] = mn;
    sRstd[tid] = rsqrtf(SS * (1.f / 256.f) - mn * mn + 1e-5f);
  }
  __syncthreads();
  {
    float mnv[4][4], rsv[4][4];
    #pragma unroll
    for (int mt = 0; mt < 4; ++mt)
      #pragma unroll
      for (int r = 0; r < 4; ++r) {
        const int m_ = mt * 16 + q * 4 + r;
        mnv[mt][r] = sMean[m_]; rsv[mt][r] = sRstd[m_];
      }
    #pragma unroll
    for (int mt = 0; mt < 4; ++mt) {
      #pragma unroll
      for (int ntl = 0; ntl < 4; ++ntl) {
        const int col = w * 64 + ntl * 16 + l15;
        const int kt = col >> 5;
        const int quad2 = (col >> 3) & 3;
        const int jj = col & 7;
        #pragma unroll
        for (int r = 0; r < 4; ++r) {
          const float tn = (tpre[mt][ntl][r] - mnv[mt][r]) * rsv[mt][r] * gam1[ntl] + bet1[ntl];
          const int lane2 = quad2 * 16 + q * 4 + r;
          sAp[((mt * 8 + kt) * 64 + SWZ(lane2)) * 8 + jj] = f2bf(tn);
        }
      }
    }
  }
  __syncthreads();

  // ---- phase 4: chunked MLP: acc3 = relu(t@We1)@We2 ----
  f32x4 acc3[4][4];
  #pragma unroll
  for (int mt = 0; mt < 4; ++mt)
    #pragma unroll
    for (int ntl = 0; ntl < 4; ++ntl)
      acc3[mt][ntl] = (f32x4){0.f, 0.f, 0.f, 0.f};

  #pragma unroll 1
  for (int c = 0; c < 4; ++c) {
    f32x4 acc2[4][4];
    #pragma unroll
    for (int mt = 0; mt < 4; ++mt)
      #pragma unroll
      for (int ntl = 0; ntl < 4; ++ntl)
        acc2[mt][ntl] = (f32x4){0.f, 0.f, 0.f, 0.f};
    #pragma unroll
    for (int kt = 0; kt < 8; ++kt) {
      bf16x8 a[4];
      #pragma unroll
      for (int mt = 0; mt < 4; ++mt)
        a[mt] = ld_frag(&sAp[((mt * 8 + kt) * 64 + lane_sw) * 8]);
      #pragma unroll
      for (int ntl = 0; ntl < 4; ++ntl) {
        const bf16x8 bfr = ld_frag(&We1p[((size_t)((kt * 64 + c * 16 + 4 * w + ntl) * 64 + lane)) * 8]);
        #pragma unroll
        for (int mt = 0; mt < 4; ++mt)
          acc2[mt][ntl] = __builtin_amdgcn_mfma_f32_16x16x32_bf16(a[mt], bfr, acc2[mt][ntl], 0, 0, 0);
      }
    }
    __syncthreads();   // prior GEMM3 reads of sScr complete
    // h1 = relu(acc2 + be1) -> bf16 -> sScr (swizzled A-frag layout)
    #pragma unroll
    for (int ntl = 0; ntl < 4; ++ntl) {
      const int flocal = w * 64 + ntl * 16 + l15;
      const float bias = be1[c * 256 + flocal];
      const int ktl = 2 * w + (ntl >> 1);
      const int quad2 = (ntl * 2 + (l15 >> 3)) & 3;
      const int jj = l15 & 7;
      #pragma unroll
      for (int mt = 0; mt < 4; ++mt) {
        #pragma unroll
        for (int r = 0; r < 4; ++r) {
          const int lane2 = quad2 * 16 + q * 4 + r;
          const float h = fmaxf(acc2[mt][ntl][r] + bias, 0.f);
          sScr[((mt * 8 + ktl) * 64 + SWZ(lane2)) * 8 + jj] = f2bf(h);
        }
      }
    }
    __syncthreads();
    #pragma unroll
    for (int kt2 = 0; kt2 < 8; ++kt2) {
      bf16x8 a[4];
      #pragma unroll
      for (int mt = 0; mt < 4; ++mt)
        a[mt] = ld_frag(&sScr[((mt * 8 + kt2) * 64 + lane_sw) * 8]);
      #pragma unroll
      for (int ntl = 0; ntl < 4; ++ntl) {
        const bf16x8 bfr = ld_frag(&We2p[((size_t)(((c * 8 + kt2) * 16 + 4 * w + ntl) * 64 + lane)) * 8]);
        #pragma unroll
        for (int mt = 0; mt < 4; ++mt)
          acc3[mt][ntl] = __builtin_amdgcn_mfma_f32_16x16x32_bf16(a[mt], bfr, acc3[mt][ntl], 0, 0, 0);
      }
    }
  }

  // ---- phase 5: ypre = acc3 + be2 + t; LN2; store ----
  float ypre[4][4][4];
  #pragma unroll
  for (int mt = 0; mt < 4; ++mt) {
    #pragma unroll
    for (int ntl = 0; ntl < 4; ++ntl) {
      const int col = w * 64 + ntl * 16 + l15;
      const int kt = col >> 5;
      const int quad2 = (col >> 3) & 3;
      const int jj = col & 7;
      #pragma unroll
      for (int r = 0; r < 4; ++r) {
        const int lane2 = quad2 * 16 + q * 4 + r;
        const float tres = bf2f(sAp[((mt * 8 + kt) * 64 + SWZ(lane2)) * 8 + jj]);
        ypre[mt][ntl][r] = acc3[mt][ntl][r] + be2c[ntl] + tres;
      }
    }
  }
  #pragma unroll
  for (int mt = 0; mt < 4; ++mt) {
    #pragma unroll
    for (int r = 0; r < 4; ++r) {
      float s = 0.f, ss = 0.f;
      #pragma unroll
      for (int ntl = 0; ntl < 4; ++ntl) {
        const float v = ypre[mt][ntl][r];
        s += v; ss += v * v;
      }
      #pragma unroll
      for (int off = 1; off < 16; off <<= 1) {
        s += __shfl_xor(s, off, 64);
        ss += __shfl_xor(ss, off, 64);
      }
      if (l15 == 0) {
        const int m_ = mt * 16 + q * 4 + r;
        sSum[m_][w] = s; sSsq[m_][w] = ss;
      }
    }
  }
  __syncthreads();
  if (tid < 64) {
    const float S = sSum[tid][0] + sSum[tid][1] + sSum[tid][2] + sSum[tid][3];
    const float SS = sSsq[tid][0] + sSsq[tid][1] + sSsq[tid][2] + sSsq[tid][3];
    const float mn = S * (1.f / 256.f);
    sMean[tid] = mn;
    sRstd[tid] = rsqrtf(SS * (1.f / 256.f) - mn * mn + 1e-5f);
  }
  __syncthreads();
  #pragma unroll
  for (int mt = 0; mt < 4; ++mt) {
    #pragma unroll
    for (int r = 0; r < 4; ++r) {
      const int m_ = mt * 16 + q * 4 + r;
      const float mn = sMean[m_], rs = sRstd[m_];
      #pragma unroll
      for (int ntl = 0; ntl < 4; ++ntl) {
        const int col = w * 64 + ntl * 16 + l15;
        const float y = (ypre[mt][ntl][r] - mn) * rs * gam2[ntl] + bet2[ntl];
        out_edges[((size_t)bi * NNODE + j0 + m_) * EE + col] = y;
      }
    }
  }
}

// ---------------- softmax ----------------
__global__ __launch_bounds__(64) void softmax_kernel(float* __restrict__ logits) {
  const int row = blockIdx.x;
  const int l = threadIdx.x;
  float* p = logits + (size_t)row * NNODE;
  float v0 = p[l], v1 = p[l + 64], v2 = p[l + 128], v3 = p[l + 192];
  float m = fmaxf(fmaxf(v0, v1), fmaxf(v2, v3));
  #pragma unroll
  for (int off = 32; off > 0; off >>= 1) m = fmaxf(m, __shfl_xor(m, off, 64));
  const float e0 = __expf(v0 - m), e1 = __expf(v1 - m), e2 = __expf(v2 - m), e3 = __expf(v3 - m);
  float s = e0 + e1 + e2 + e3;
  #pragma unroll
  for (int off = 32; off > 0; off >>= 1) s += __shfl_xor(s, off, 64);
  const float inv = 1.f / s;
  p[l] = e0 * inv; p[l + 64] = e1 * inv; p[l + 128] = e2 * inv; p[l + 192] = e3 * inv;
}

// ---------------- fused node path ----------------
__global__ __launch_bounds__(256) void node_kernel(
    const float* __restrict__ attn, const float* __restrict__ V,
    const float* __restrict__ nodes,
    const float* __restrict__ WnoT, const float* __restrict__ bno,
    const float* __restrict__ g1n, const float* __restrict__ b1n,
    const float* __restrict__ Wn1T, const float* __restrict__ bn1,
    const float* __restrict__ Wn2T, const float* __restrict__ bn2,
    const float* __restrict__ g2n, const float* __restrict__ b2n,
    float* __restrict__ out_nodes)
{
  __shared__ float sA[HH][NNODE];
  __shared__ float sX[DD];
  __shared__ float sH[FF];
  __shared__ float red[8];
  __shared__ float mv[2];

  const int row = blockIdx.x;
  const int b = row >> 8;
  const int tid = threadIdx.x;

  for (int t = tid; t < HH * NNODE; t += 256)
    sA[t >> 8][t & 255] = attn[(size_t)row * (HH * NNODE) + t];
  __syncthreads();

  const int h = tid >> 5;
  float wv = 0.f;
  for (int j = 0; j < NNODE; ++j)
    wv = fmaf(sA[h][j], V[(b * NNODE + j) * DD + tid], wv);
  sX[tid] = wv;
  __syncthreads();

  float a1 = bno[tid];
  for (int d = 0; d < DD; d += 4) {
    const float4 x = *(const float4*)&sX[d];
    const float* wp = &WnoT[d * DD + tid];
    a1 = fmaf(x.x, wp[0], a1);
    a1 = fmaf(x.y, wp[DD], a1);
    a1 = fmaf(x.z, wp[2 * DD], a1);
    a1 = fmaf(x.w, wp[3 * DD], a1);
  }
  a1 += nodes[(size_t)row * DD + tid];

  float x1;
  {
    float s = a1, ss = a1 * a1;
    #pragma unroll
    for (int off = 32; off > 0; off >>= 1) { s += __shfl_xor(s, off, 64); ss += __shfl_xor(ss, off, 64); }
    if ((tid & 63) == 0) { red[tid >> 6] = s; red[4 + (tid >> 6)] = ss; }
    __syncthreads();
    if (tid == 0) {
      const float S = red[0] + red[1] + red[2] + red[3];
      const float SS = red[4] + red[5] + red[6] + red[7];
      const float m = S * (1.f / 256.f);
      mv[0] = m; mv[1] = rsqrtf(SS * (1.f / 256.f) - m * m + 1e-5f);
    }
    __syncthreads();
    x1 = (a1 - mv[0]) * mv[1] * g1n[tid] + b1n[tid];
  }
  sX[tid] = x1;
  __syncthreads();

  float h1[4];
  #pragma unroll
  for (int p = 0; p < 4; ++p) h1[p] = bn1[p * 256 + tid];
  for (int d = 0; d < DD; d += 4) {
    const float4 x = *(const float4*)&sX[d];
    #pragma unroll
    for (int p = 0; p < 4; ++p) {
      const float* wp = &Wn1T[d * FF + p * 256 + tid];
      h1[p] = fmaf(x.x, wp[0], h1[p]);
      h1[p] = fmaf(x.y, wp[FF], h1[p]);
      h1[p] = fmaf(x.z, wp[2 * FF], h1[p]);
      h1[p] = fmaf(x.w, wp[3 * FF], h1[p]);
    }
  }
  #pragma unroll
  for (int p = 0; p < 4; ++p) sH[p * 256 + tid] = fmaxf(h1[p], 0.f);
  __syncthreads();

  float a2 = bn2[tid];
  for (int f = 0; f < FF; f += 4) {
    const float4 x = *(const float4*)&sH[f];
    const float* wp = &Wn2T[f * DD + tid];
    a2 = fmaf(x.x, wp[0], a2);
    a2 = fmaf(x.y, wp[DD], a2);
    a2 = fmaf(x.z, wp[2 * DD], a2);
    a2 = fmaf(x.w, wp[3 * DD], a2);
  }
  a2 += x1;

  {
    float s = a2, ss = a2 * a2;
    #pragma unroll
    for (int off = 32; off > 0; off >>= 1) { s += __shfl_xor(s, off, 64); ss += __shfl_xor(ss, off, 64); }
    if ((tid & 63) == 0) { red[tid >> 6] = s; red[4 + (tid >> 6)] = ss; }
    __syncthreads();
    if (tid == 0) {
      const float S = red[0] + red[1] + red[2] + red[3];
      const float SS = red[4] + red[5] + red[6] + red[7];
      const float m = S * (1.f / 256.f);
      mv[0] = m; mv[1] = rsqrtf(SS * (1.f / 256.f) - m * m + 1e-5f);
    }
    __syncthreads();
    out_nodes[(size_t)row * DD + tid] = (a2 - mv[0]) * mv[1] * g2n[tid] + b2n[tid];
  }
}

extern "C" void kernel_launch(void* const* d_in, const int* in_sizes, int n_in,
                              void* d_out, int out_size, void* d_ws, size_t ws_size,
                              hipStream_t stream) {
  const float* nodes = (const float*)d_in[0];
  const float* edges = (const float*)d_in[1];
  const float* conds = (const float*)d_in[2];
  const float* Wqkv = (const float*)d_in[3];
  const float* bqkv = (const float*)d_in[4];
  const float* Wno  = (const float*)d_in[5];
  const float* bno  = (const float*)d_in[6];
  const float* Weo  = (const float*)d_in[7];
  const float* beo  = (const float*)d_in[8];
  const float* g1n  = (const float*)d_in[9];
  const float* b1n  = (const float*)d_in[10];
  const float* g1e  = (const float*)d_in[11];
  const float* b1e  = (const float*)d_in[12];
  const float* Wn1  = (const float*)d_in[13];
  const float* bn1  = (const float*)d_in[14];
  const float* Wn2  = (const float*)d_in[15];
  const float* bn2  = (const float*)d_in[16];
  const float* We1  = (const float*)d_in[17];
  const float* be1  = (const float*)d_in[18];
  const float* We2  = (const float*)d_in[19];
  const float* be2  = (const float*)d_in[20];
  const float* g2n  = (const float*)d_in[21];
  const float* b2n  = (const float*)d_in[22];
  const float* g2e  = (const float*)d_in[23];
  const float* b2e  = (const float*)d_in[24];

  float* ws = (float*)d_ws;
  float* Q = ws;
  float* K = Q + BB * NNODE * DD;
  float* V = K + BB * NNODE * DD;
  float* logits = V + BB * NNODE * DD;                 // B*N*H*N
  float* WqkvT = logits + BB * NNODE * HH * NNODE;
  float* WnoT = WqkvT + 3 * DD * DD;
  float* Wn1T = WnoT + DD * DD;
  float* Wn2T = Wn1T + DD * FF;
  unsigned short* Weop = (unsigned short*)(Wn2T + FF * DD);
  unsigned short* We1p = Weop + EE * DD;
  unsigned short* We2p = We1p + FF * DD;

  float* out_nodes = (float*)d_out;
  float* out_edges = out_nodes + BB * NNODE * DD;
  float* out_conds = out_edges + (size_t)BB * NNODE * NNODE * EE;

  auto T = [&](const float* src, float* dst, int rows, int cols) {
    int n = rows * cols;
    transpose_kernel<<<(n + 255) / 256, 256, 0, stream>>>(src, dst, rows, cols);
  };
  T(Wqkv, WqkvT, 3 * DD, DD);
  T(Wno, WnoT, DD, DD);
  T(Wn1, Wn1T, FF, DD);
  T(Wn2, Wn2T, DD, FF);

  auto P = [&](const float* src, unsigned short* dst, int K_, int Nn_) {
    int total = (K_ >> 5) * (Nn_ >> 4) * 64;
    pack_b_kernel<<<(total + 255) / 256, 256, 0, stream>>>(src, dst, K_, Nn_);
  };
  P(Weo, Weop, DD, EE);
  P(We1, We1p, DD, FF);
  P(We2, We2p, FF, EE);

  qkv_kernel<<<BB * NNODE, 256, 0, stream>>>(nodes, conds, WqkvT, bqkv, Q, K, V);
  edge_mfma_kernel<<<BB * NNODE * (NNODE / 64), 256, 0, stream>>>(
      Q, K, edges, Weop, beo, g1e, b1e, We1p, be1, We2p, be2, g2e, b2e,
      logits, out_edges);
  softmax_kernel<<<BB * NNODE * HH, 64, 0, stream>>>(logits);
  node_kernel<<<BB * NNODE, 256, 0, stream>>>(
      logits, V, nodes, WnoT, bno, g1n, b1n, Wn1T, bn1, Wn2T, bn2, g2n, b2n,
      out_nodes);

  hipMemcpyAsync(out_conds, conds, BB * DD * sizeof(float),
                 hipMemcpyDeviceToDevice, stream);
}

// Round 4
// 913.348 us; speedup vs baseline: 1.3141x; 1.3141x over previous
//
#include <hip/hip_runtime.h>
#include <hip/hip_bf16.h>
#include <math.h>

constexpr int BB = 2;
constexpr int NNODE = 256;   // N
constexpr int DD = 256;      // D == E
constexpr int HH = 8;
constexpr int EE = 256;
constexpr int FF = 1024;     // 4*E

typedef __bf16 bf16x8 __attribute__((ext_vector_type(8)));
typedef float f32x4 __attribute__((ext_vector_type(4)));
typedef unsigned int uint4v __attribute__((ext_vector_type(4)));

// swizzle: xor low 2 bits with bits 4-5 -> spreads q-groups across bank groups
#define SWZB(x) ((x) ^ (((x) >> 4) & 3))

__device__ __forceinline__ unsigned short f2bf(float f) {
  unsigned u = __builtin_bit_cast(unsigned, f);
  unsigned r = u + 0x7FFFu + ((u >> 16) & 1u);
  return (unsigned short)(r >> 16);
}
__device__ __forceinline__ float bf2f(unsigned short us) {
  return __builtin_bit_cast(float, (unsigned)us << 16);
}
__device__ __forceinline__ bf16x8 ld_frag(const unsigned short* p) {
  uint4v u = *(const uint4v*)p;
  return __builtin_bit_cast(bf16x8, u);
}

// ---------------- merged weight-prep kernel ----------------
__device__ __forceinline__ void d_transpose(const float* __restrict__ src,
                                            float* __restrict__ dst,
                                            int rows, int cols, int idx) {
  int r = idx / cols, c = idx - r * cols;
  dst[c * rows + r] = src[idx];
}
// B-frag pack: dst[((kt*NT+nt)*64+lane)*8+j] = bf16(src[nt*16+(lane&15)][kt*32+(lane>>4)*8+j])
__device__ __forceinline__ void d_pack(const float* __restrict__ src,
                                       unsigned short* __restrict__ dst,
                                       int K, int Nn, int idx) {
  int NT = Nn >> 4;
  int lane = idx & 63, ntkt = idx >> 6;
  int nt = ntkt % NT, kt = ntkt / NT;
  int q = lane >> 4, l15 = lane & 15;
  const float* s = src + (size_t)(nt * 16 + l15) * K + kt * 32 + q * 8;
  float4 a = *(const float4*)s;
  float4 b = *(const float4*)(s + 4);
  unsigned short* d = dst + (size_t)idx * 8;
  d[0] = f2bf(a.x); d[1] = f2bf(a.y); d[2] = f2bf(a.z); d[3] = f2bf(a.w);
  d[4] = f2bf(b.x); d[5] = f2bf(b.y); d[6] = f2bf(b.z); d[7] = f2bf(b.w);
}

__global__ __launch_bounds__(256) void prep_kernel(
    const float* __restrict__ Wqkv, float* __restrict__ WqkvT,
    const float* __restrict__ Wno,  float* __restrict__ WnoT,
    const float* __restrict__ Wn1,  float* __restrict__ Wn1T,
    const float* __restrict__ Wn2,  float* __restrict__ Wn2T,
    const float* __restrict__ Weo,  unsigned short* __restrict__ Weop,
    const float* __restrict__ We1,  unsigned short* __restrict__ We1p,
    const float* __restrict__ We2,  unsigned short* __restrict__ We2p)
{
  const int blk = blockIdx.x, tid = threadIdx.x;
  if (blk < 768)        d_transpose(Wqkv, WqkvT, 768, 256, blk * 256 + tid);
  else if (blk < 1024)  d_transpose(Wno, WnoT, 256, 256, (blk - 768) * 256 + tid);
  else if (blk < 2048)  d_transpose(Wn1, Wn1T, 1024, 256, (blk - 1024) * 256 + tid);
  else if (blk < 3072)  d_transpose(Wn2, Wn2T, 256, 1024, (blk - 2048) * 256 + tid);
  else if (blk < 3104)  d_pack(Weo, Weop, 256, 256, (blk - 3072) * 256 + tid);
  else if (blk < 3232)  d_pack(We1, We1p, 256, 1024, (blk - 3104) * 256 + tid);
  else                  d_pack(We2, We2p, 1024, 256, (blk - 3232) * 256 + tid);
}

// ---------------- qkv projection ----------------
__global__ __launch_bounds__(256) void qkv_kernel(
    const float* __restrict__ nodes, const float* __restrict__ conds,
    const float* __restrict__ WqkvT, const float* __restrict__ bqkv,
    float* __restrict__ Q, float* __restrict__ K, float* __restrict__ V)
{
  __shared__ float sX[DD];
  const int row = blockIdx.x;
  const int b = row >> 8;
  const int tid = threadIdx.x;
  sX[tid] = nodes[(size_t)row * DD + tid] + conds[b * DD + tid];
  __syncthreads();
  float aq = bqkv[tid], ak = bqkv[DD + tid], av = bqkv[2 * DD + tid];
  for (int d = 0; d < DD; d += 4) {
    const float4 x = *(const float4*)&sX[d];
    const float* wp = &WqkvT[d * (3 * DD)];
    aq = fmaf(x.x, wp[tid], aq);
    ak = fmaf(x.x, wp[DD + tid], ak);
    av = fmaf(x.x, wp[2 * DD + tid], av);
    aq = fmaf(x.y, wp[768 + tid], aq);
    ak = fmaf(x.y, wp[768 + DD + tid], ak);
    av = fmaf(x.y, wp[768 + 2 * DD + tid], av);
    aq = fmaf(x.z, wp[1536 + tid], aq);
    ak = fmaf(x.z, wp[1536 + DD + tid], ak);
    av = fmaf(x.z, wp[1536 + 2 * DD + tid], av);
    aq = fmaf(x.w, wp[2304 + tid], aq);
    ak = fmaf(x.w, wp[2304 + DD + tid], ak);
    av = fmaf(x.w, wp[2304 + 2 * DD + tid], av);
  }
  Q[(size_t)row * DD + tid] = aq;
  K[(size_t)row * DD + tid] = ak;
  V[(size_t)row * DD + tid] = av;
}

// ---------------- fused MFMA edge kernel, M=32 per block ----------------
// Block: bi = blk>>3, j0 = (blk&7)*32. 256 threads = 4 waves.
// Wave w owns output cols [64w, 64w+64) (4 n-tiles), all 2 m-tiles (32 rows).
__global__ __launch_bounds__(256, 2) void edge_mfma_kernel(
    const float* __restrict__ Q, const float* __restrict__ K,
    const float* __restrict__ edges,
    const unsigned short* __restrict__ Weop, const float* __restrict__ beo,
    const float* __restrict__ g1e, const float* __restrict__ b1e,
    const unsigned short* __restrict__ We1p, const float* __restrict__ be1,
    const unsigned short* __restrict__ We2p, const float* __restrict__ be2,
    const float* __restrict__ g2e, const float* __restrict__ b2e,
    float* __restrict__ logits, float* __restrict__ out_edges)
{
  __shared__ unsigned short sAp[2 * 8 * 64 * 8];   // 16 KB: ne5 -> t, A-frag layout (swizzled)
  __shared__ unsigned short sScr[32 * 264];        // 16.5 KB union: edges residual bf16 (row-major) -> h1 chunk (A-layout)
  __shared__ float sQ[256];
  __shared__ float sLog[32][8];
  __shared__ float sSum[32][4], sSsq[32][4];
  __shared__ float sMean[32], sRstd[32];

  const int tid = threadIdx.x;
  const int w = tid >> 6;
  const int lane = tid & 63;
  const int q = lane >> 4;
  const int l15 = lane & 15;
  const int lane_sw = SWZB(lane);

  const int blk = blockIdx.x;
  const int bi = blk >> 3;          // b*N + i
  const int b = bi >> 8;
  const int j0 = (blk & 7) * 32;

  // ---- phase 0: sQ + per-lane epilogue constants ----
  sQ[tid] = Q[(size_t)bi * DD + tid] * 0.0625f;
  float gam1[4], bet1[4], gam2[4], bet2[4], beoc[4], be2c[4];
  #pragma unroll
  for (int ntl = 0; ntl < 4; ++ntl) {
    const int c = w * 64 + ntl * 16 + l15;
    gam1[ntl] = g1e[c]; bet1[ntl] = b1e[c];
    gam2[ntl] = g2e[c]; bet2[ntl] = b2e[c];
    beoc[ntl] = beo[c]; be2c[ntl] = be2[c];
  }
  __syncthreads();

  // ---- phase 1: ne5 = q*k/16 + edges; residual bf16 -> sScr; logits partials; pack ne5 -> sAp ----
  {
    const int m = 8 * w + (lane >> 3);       // row 0..31
    const int db = lane & 7;
    const size_t krow = ((size_t)(b * NNODE + j0 + m)) * DD;
    const size_t erow = ((size_t)bi * NNODE + j0 + m) * DD;
    #pragma unroll
    for (int it = 0; it < 4; ++it) {
      const int d0 = it * 64 + db * 8;
      const float4 k0 = *(const float4*)&K[krow + d0];
      const float4 k1 = *(const float4*)&K[krow + d0 + 4];
      const float4 e0 = *(const float4*)&edges[erow + d0];
      const float4 e1 = *(const float4*)&edges[erow + d0 + 4];
      const float4 q0 = *(const float4*)&sQ[d0];
      const float4 q1 = *(const float4*)&sQ[d0 + 4];
      float f[8];
      f[0] = fmaf(q0.x, k0.x, e0.x); f[1] = fmaf(q0.y, k0.y, e0.y);
      f[2] = fmaf(q0.z, k0.z, e0.z); f[3] = fmaf(q0.w, k0.w, e0.w);
      f[4] = fmaf(q1.x, k1.x, e1.x); f[5] = fmaf(q1.y, k1.y, e1.y);
      f[6] = fmaf(q1.z, k1.z, e1.z); f[7] = fmaf(q1.w, k1.w, e1.w);
      // edges residual, bf16, row-major stride 264
      uint4v ep;
      ep.x = (unsigned)f2bf(e0.x) | ((unsigned)f2bf(e0.y) << 16);
      ep.y = (unsigned)f2bf(e0.z) | ((unsigned)f2bf(e0.w) << 16);
      ep.z = (unsigned)f2bf(e1.x) | ((unsigned)f2bf(e1.y) << 16);
      ep.w = (unsigned)f2bf(e1.z) | ((unsigned)f2bf(e1.w) << 16);
      *(uint4v*)&sScr[m * 264 + d0] = ep;
      // logits partial: 32-chunk h = it*2 + (db>>2)
      float s = f[0] + f[1] + f[2] + f[3] + f[4] + f[5] + f[6] + f[7];
      s += __shfl_xor(s, 1, 64);
      s += __shfl_xor(s, 2, 64);
      if ((lane & 3) == 0) sLog[m][2 * it + (db >> 2)] = s;
      // pack ne5 bf16 into swizzled A-frag layout
      const int kt = 2 * it + (db >> 2);
      const int quad = db & 3;
      const int mt = m >> 4;
      const int lane2 = quad * 16 + (m & 15);
      uint4v pk;
      pk.x = (unsigned)f2bf(f[0]) | ((unsigned)f2bf(f[1]) << 16);
      pk.y = (unsigned)f2bf(f[2]) | ((unsigned)f2bf(f[3]) << 16);
      pk.z = (unsigned)f2bf(f[4]) | ((unsigned)f2bf(f[5]) << 16);
      pk.w = (unsigned)f2bf(f[6]) | ((unsigned)f2bf(f[7]) << 16);
      *(uint4v*)&sAp[((mt * 8 + kt) * 64 + SWZB(lane2)) * 8] = pk;
    }
  }

  // GEMM1 B preload (issued before the barrier so loads fly during the wait)
  bf16x8 Bf[2][4];
  #pragma unroll
  for (int p = 0; p < 2; ++p)
    #pragma unroll
    for (int ntl = 0; ntl < 4; ++ntl)
      Bf[p][ntl] = ld_frag(&Weop[((size_t)((p * 16 + 4 * w + ntl) * 64 + lane)) * 8]);
  __syncthreads();

  // ---- phase 2: GEMM1  C1[32x256] = ne5 @ Weo^T, depth-2 B prefetch ----
  f32x4 acc1[2][4];
  #pragma unroll
  for (int mt = 0; mt < 2; ++mt)
    #pragma unroll
    for (int ntl = 0; ntl < 4; ++ntl)
      acc1[mt][ntl] = (f32x4){0.f, 0.f, 0.f, 0.f};
  #pragma unroll
  for (int kt = 0; kt < 8; ++kt) {
    const bf16x8 a0 = ld_frag(&sAp[((0 * 8 + kt) * 64 + lane_sw) * 8]);
    const bf16x8 a1 = ld_frag(&sAp[((1 * 8 + kt) * 64 + lane_sw) * 8]);
    const bf16x8 b0 = Bf[kt & 1][0], b1 = Bf[kt & 1][1], b2 = Bf[kt & 1][2], b3 = Bf[kt & 1][3];
    if (kt < 6) {
      #pragma unroll
      for (int ntl = 0; ntl < 4; ++ntl)
        Bf[kt & 1][ntl] = ld_frag(&Weop[((size_t)(((kt + 2) * 16 + 4 * w + ntl) * 64 + lane)) * 8]);
    }
    acc1[0][0] = __builtin_amdgcn_mfma_f32_16x16x32_bf16(a0, b0, acc1[0][0], 0, 0, 0);
    acc1[1][0] = __builtin_amdgcn_mfma_f32_16x16x32_bf16(a1, b0, acc1[1][0], 0, 0, 0);
    acc1[0][1] = __builtin_amdgcn_mfma_f32_16x16x32_bf16(a0, b1, acc1[0][1], 0, 0, 0);
    acc1[1][1] = __builtin_amdgcn_mfma_f32_16x16x32_bf16(a1, b1, acc1[1][1], 0, 0, 0);
    acc1[0][2] = __builtin_amdgcn_mfma_f32_16x16x32_bf16(a0, b2, acc1[0][2], 0, 0, 0);
    acc1[1][2] = __builtin_amdgcn_mfma_f32_16x16x32_bf16(a1, b2, acc1[1][2], 0, 0, 0);
    acc1[0][3] = __builtin_amdgcn_mfma_f32_16x16x32_bf16(a0, b3, acc1[0][3], 0, 0, 0);
    acc1[1][3] = __builtin_amdgcn_mfma_f32_16x16x32_bf16(a1, b3, acc1[1][3], 0, 0, 0);
  }

  // logits out (off the critical path; sLog ordered by the phase-1 barrier)
  {
    const int h = tid >> 5, mm = tid & 31;
    logits[((size_t)bi * HH + h) * NNODE + j0 + mm] = sLog[mm][h];
  }

  // ---- phase 3: tpre = relu(C1+beo) + edges; LN1; t -> sAp ----
  float tpre[2][4][4];
  #pragma unroll
  for (int mt = 0; mt < 2; ++mt) {
    #pragma unroll
    for (int r = 0; r < 4; ++r) {
      const int m_ = mt * 16 + q * 4 + r;
      #pragma unroll
      for (int ntl = 0; ntl < 4; ++ntl) {
        const int col = w * 64 + ntl * 16 + l15;
        const float ed = bf2f(sScr[m_ * 264 + col]);
        tpre[mt][ntl][r] = fmaxf(acc1[mt][ntl][r] + beoc[ntl], 0.f) + ed;
      }
    }
  }
  #pragma unroll
  for (int mt = 0; mt < 2; ++mt) {
    #pragma unroll
    for (int r = 0; r < 4; ++r) {
      float s = 0.f, ss = 0.f;
      #pragma unroll
      for (int ntl = 0; ntl < 4; ++ntl) {
        const float v = tpre[mt][ntl][r];
        s += v; ss += v * v;
      }
      #pragma unroll
      for (int off = 1; off < 16; off <<= 1) {
        s += __shfl_xor(s, off, 64);
        ss += __shfl_xor(ss, off, 64);
      }
      if (l15 == 0) {
        const int m_ = mt * 16 + q * 4 + r;
        sSum[m_][w] = s; sSsq[m_][w] = ss;
      }
    }
  }
  __syncthreads();
  if (tid < 32) {
    const float S = sSum[tid][0] + sSum[tid][1] + sSum[tid][2] + sSum[tid][3];
    const float SS = sSsq[tid][0] + sSsq[tid][1] + sSsq[tid][2] + sSsq[tid][3];
    const float mn = S * (1.f / 256.f);
    sMean[tid] = mn;
    sRstd[tid] = rsqrtf(SS * (1.f / 256.f) - mn * mn + 1e-5f);
  }
  __syncthreads();
  #pragma unroll
  for (int mt = 0; mt < 2; ++mt) {
    #pragma unroll
    for (int ntl = 0; ntl < 4; ++ntl) {
      const int col = w * 64 + ntl * 16 + l15;
      const int kt = col >> 5;
      const int quad2 = (col >> 3) & 3;
      const int jj = col & 7;
      #pragma unroll
      for (int r = 0; r < 4; ++r) {
        const int m_ = mt * 16 + q * 4 + r;
        const float tn = (tpre[mt][ntl][r] - sMean[m_]) * sRstd[m_] * gam1[ntl] + bet1[ntl];
        const int lane2 = quad2 * 16 + q * 4 + r;
        sAp[((mt * 8 + kt) * 64 + SWZB(lane2)) * 8 + jj] = f2bf(tn);
      }
    }
  }
  // GEMM2 c=0 B preload before the barrier
  #pragma unroll
  for (int p = 0; p < 2; ++p)
    #pragma unroll
    for (int ntl = 0; ntl < 4; ++ntl)
      Bf[p][ntl] = ld_frag(&We1p[((size_t)((p * 64 + 0 * 16 + 4 * w + ntl) * 64 + lane)) * 8]);
  __syncthreads();

  // ---- phase 4: chunked MLP: acc3 = relu(t@We1)@We2 ----
  f32x4 acc3[2][4];
  #pragma unroll
  for (int mt = 0; mt < 2; ++mt)
    #pragma unroll
    for (int ntl = 0; ntl < 4; ++ntl)
      acc3[mt][ntl] = (f32x4){0.f, 0.f, 0.f, 0.f};

  #pragma unroll 1
  for (int c = 0; c < 4; ++c) {
    // GEMM2: h1chunk[32x256] = t @ We1^T[:, 256c:256c+256], depth-2 prefetch
    f32x4 acc2[2][4];
    #pragma unroll
    for (int mt = 0; mt < 2; ++mt)
      #pragma unroll
      for (int ntl = 0; ntl < 4; ++ntl)
        acc2[mt][ntl] = (f32x4){0.f, 0.f, 0.f, 0.f};
    #pragma unroll
    for (int kt = 0; kt < 8; ++kt) {
      const bf16x8 a0 = ld_frag(&sAp[((0 * 8 + kt) * 64 + lane_sw) * 8]);
      const bf16x8 a1 = ld_frag(&sAp[((1 * 8 + kt) * 64 + lane_sw) * 8]);
      const bf16x8 b0 = Bf[kt & 1][0], b1 = Bf[kt & 1][1], b2 = Bf[kt & 1][2], b3 = Bf[kt & 1][3];
      if (kt < 6) {
        #pragma unroll
        for (int ntl = 0; ntl < 4; ++ntl)
          Bf[kt & 1][ntl] = ld_frag(&We1p[((size_t)(((kt + 2) * 64 + c * 16 + 4 * w + ntl) * 64 + lane)) * 8]);
      }
      acc2[0][0] = __builtin_amdgcn_mfma_f32_16x16x32_bf16(a0, b0, acc2[0][0], 0, 0, 0);
      acc2[1][0] = __builtin_amdgcn_mfma_f32_16x16x32_bf16(a1, b0, acc2[1][0], 0, 0, 0);
      acc2[0][1] = __builtin_amdgcn_mfma_f32_16x16x32_bf16(a0, b1, acc2[0][1], 0, 0, 0);
      acc2[1][1] = __builtin_amdgcn_mfma_f32_16x16x32_bf16(a1, b1, acc2[1][1], 0, 0, 0);
      acc2[0][2] = __builtin_amdgcn_mfma_f32_16x16x32_bf16(a0, b2, acc2[0][2], 0, 0, 0);
      acc2[1][2] = __builtin_amdgcn_mfma_f32_16x16x32_bf16(a1, b2, acc2[1][2], 0, 0, 0);
      acc2[0][3] = __builtin_amdgcn_mfma_f32_16x16x32_bf16(a0, b3, acc2[0][3], 0, 0, 0);
      acc2[1][3] = __builtin_amdgcn_mfma_f32_16x16x32_bf16(a1, b3, acc2[1][3], 0, 0, 0);
    }
    // GEMM3 B preload (independent of sScr; flies across the barrier + pack)
    #pragma unroll
    for (int p = 0; p < 2; ++p)
      #pragma unroll
      for (int ntl = 0; ntl < 4; ++ntl)
        Bf[p][ntl] = ld_frag(&We2p[((size_t)(((c * 8 + p) * 16 + 4 * w + ntl) * 64 + lane)) * 8]);
    __syncthreads();   // prior GEMM3 (or phase-3 residual) reads of sScr complete
    // h1 = relu(acc2 + be1) -> bf16 -> sScr (swizzled A-frag layout)
    #pragma unroll
    for (int ntl = 0; ntl < 4; ++ntl) {
      const int flocal = w * 64 + ntl * 16 + l15;
      const float bias = be1[c * 256 + flocal];
      const int ktl = 2 * w + (ntl >> 1);
      const int quad2 = (ntl * 2 + (l15 >> 3)) & 3;
      const int jj = l15 & 7;
      #pragma unroll
      for (int mt = 0; mt < 2; ++mt) {
        #pragma unroll
        for (int r = 0; r < 4; ++r) {
          const int lane2 = quad2 * 16 + q * 4 + r;
          const float h = fmaxf(acc2[mt][ntl][r] + bias, 0.f);
          sScr[((mt * 8 + ktl) * 64 + SWZB(lane2)) * 8 + jj] = f2bf(h);
        }
      }
    }
    __syncthreads();
    // GEMM3 accumulate: out += h1chunk @ We2^T[f-chunk], depth-2 prefetch
    #pragma unroll
    for (int kt2 = 0; kt2 < 8; ++kt2) {
      const bf16x8 a0 = ld_frag(&sScr[((0 * 8 + kt2) * 64 + lane_sw) * 8]);
      const bf16x8 a1 = ld_frag(&sScr[((1 * 8 + kt2) * 64 + lane_sw) * 8]);
      const bf16x8 b0 = Bf[kt2 & 1][0], b1 = Bf[kt2 & 1][1], b2 = Bf[kt2 & 1][2], b3 = Bf[kt2 & 1][3];
      if (kt2 < 6) {
        #pragma unroll
        for (int ntl = 0; ntl < 4; ++ntl)
          Bf[kt2 & 1][ntl] = ld_frag(&We2p[((size_t)(((c * 8 + kt2 + 2) * 16 + 4 * w + ntl) * 64 + lane)) * 8]);
      } else if (c < 3) {
        // GEMM2 preload for next c
        #pragma unroll
        for (int ntl = 0; ntl < 4; ++ntl)
          Bf[kt2 & 1][ntl] = ld_frag(&We1p[((size_t)(((kt2 - 6) * 64 + (c + 1) * 16 + 4 * w + ntl) * 64 + lane)) * 8]);
      }
      acc3[0][0] = __builtin_amdgcn_mfma_f32_16x16x32_bf16(a0, b0, acc3[0][0], 0, 0, 0);
      acc3[1][0] = __builtin_amdgcn_mfma_f32_16x16x32_bf16(a1, b0, acc3[1][0], 0, 0, 0);
      acc3[0][1] = __builtin_amdgcn_mfma_f32_16x16x32_bf16(a0, b1, acc3[0][1], 0, 0, 0);
      acc3[1][1] = __builtin_amdgcn_mfma_f32_16x16x32_bf16(a1, b1, acc3[1][1], 0, 0, 0);
      acc3[0][2] = __builtin_amdgcn_mfma_f32_16x16x32_bf16(a0, b2, acc3[0][2], 0, 0, 0);
      acc3[1][2] = __builtin_amdgcn_mfma_f32_16x16x32_bf16(a1, b2, acc3[1][2], 0, 0, 0);
      acc3[0][3] = __builtin_amdgcn_mfma_f32_16x16x32_bf16(a0, b3, acc3[0][3], 0, 0, 0);
      acc3[1][3] = __builtin_amdgcn_mfma_f32_16x16x32_bf16(a1, b3, acc3[1][3], 0, 0, 0);
    }
  }

  // ---- phase 5: ypre = acc3 + be2 + t; LN2; store ----
  float ypre[2][4][4];
  #pragma unroll
  for (int mt = 0; mt < 2; ++mt) {
    #pragma unroll
    for (int ntl = 0; ntl < 4; ++ntl) {
      const int col = w * 64 + ntl * 16 + l15;
      const int kt = col >> 5;
      const int quad2 = (col >> 3) & 3;
      const int jj = col & 7;
      #pragma unroll
      for (int r = 0; r < 4; ++r) {
        const int lane2 = quad2 * 16 + q * 4 + r;
        const float tres = bf2f(sAp[((mt * 8 + kt) * 64 + SWZB(lane2)) * 8 + jj]);
        ypre[mt][ntl][r] = acc3[mt][ntl][r] + be2c[ntl] + tres;
      }
    }
  }
  #pragma unroll
  for (int mt = 0; mt < 2; ++mt) {
    #pragma unroll
    for (int r = 0; r < 4; ++r) {
      float s = 0.f, ss = 0.f;
      #pragma unroll
      for (int ntl = 0; ntl < 4; ++ntl) {
        const float v = ypre[mt][ntl][r];
        s += v; ss += v * v;
      }
      #pragma unroll
      for (int off = 1; off < 16; off <<= 1) {
        s += __shfl_xor(s, off, 64);
        ss += __shfl_xor(ss, off, 64);
      }
      if (l15 == 0) {
        const int m_ = mt * 16 + q * 4 + r;
        sSum[m_][w] = s; sSsq[m_][w] = ss;
      }
    }
  }
  __syncthreads();
  if (tid < 32) {
    const float S = sSum[tid][0] + sSum[tid][1] + sSum[tid][2] + sSum[tid][3];
    const float SS = sSsq[tid][0] + sSsq[tid][1] + sSsq[tid][2] + sSsq[tid][3];
    const float mn = S * (1.f / 256.f);
    sMean[tid] = mn;
    sRstd[tid] = rsqrtf(SS * (1.f / 256.f) - mn * mn + 1e-5f);
  }
  __syncthreads();
  #pragma unroll
  for (int mt = 0; mt < 2; ++mt) {
    #pragma unroll
    for (int r = 0; r < 4; ++r) {
      const int m_ = mt * 16 + q * 4 + r;
      const float mn = sMean[m_], rs = sRstd[m_];
      #pragma unroll
      for (int ntl = 0; ntl < 4; ++ntl) {
        const int col = w * 64 + ntl * 16 + l15;
        const float y = (ypre[mt][ntl][r] - mn) * rs * gam2[ntl] + bet2[ntl];
        out_edges[((size_t)bi * NNODE + j0 + m_) * EE + col] = y;
      }
    }
  }
}

// ---------------- softmax ----------------
__global__ __launch_bounds__(64) void softmax_kernel(float* __restrict__ logits) {
  const int row = blockIdx.x;
  const int l = threadIdx.x;
  float* p = logits + (size_t)row * NNODE;
  float v0 = p[l], v1 = p[l + 64], v2 = p[l + 128], v3 = p[l + 192];
  float m = fmaxf(fmaxf(v0, v1), fmaxf(v2, v3));
  #pragma unroll
  for (int off = 32; off > 0; off >>= 1) m = fmaxf(m, __shfl_xor(m, off, 64));
  const float e0 = __expf(v0 - m), e1 = __expf(v1 - m), e2 = __expf(v2 - m), e3 = __expf(v3 - m);
  float s = e0 + e1 + e2 + e3;
  #pragma unroll
  for (int off = 32; off > 0; off >>= 1) s += __shfl_xor(s, off, 64);
  const float inv = 1.f / s;
  p[l] = e0 * inv; p[l + 64] = e1 * inv; p[l + 128] = e2 * inv; p[l + 192] = e3 * inv;
}

// ---------------- fused node path ----------------
__global__ __launch_bounds__(256) void node_kernel(
    const float* __restrict__ attn, const float* __restrict__ V,
    const float* __restrict__ nodes,
    const float* __restrict__ WnoT, const float* __restrict__ bno,
    const float* __restrict__ g1n, const float* __restrict__ b1n,
    const float* __restrict__ Wn1T, const float* __restrict__ bn1,
    const float* __restrict__ Wn2T, const float* __restrict__ bn2,
    const float* __restrict__ g2n, const float* __restrict__ b2n,
    float* __restrict__ out_nodes)
{
  __shared__ float sA[HH][NNODE];
  __shared__ float sX[DD];
  __shared__ float sH[FF];
  __shared__ float red[8];
  __shared__ float mv[2];

  const int row = blockIdx.x;
  const int b = row >> 8;
  const int tid = threadIdx.x;

  for (int t = tid; t < HH * NNODE; t += 256)
    sA[t >> 8][t & 255] = attn[(size_t)row * (HH * NNODE) + t];
  __syncthreads();

  const int h = tid >> 5;
  float wv = 0.f;
  for (int j = 0; j < NNODE; ++j)
    wv = fmaf(sA[h][j], V[(b * NNODE + j) * DD + tid], wv);
  sX[tid] = wv;
  __syncthreads();

  float a1 = bno[tid];
  for (int d = 0; d < DD; d += 4) {
    const float4 x = *(const float4*)&sX[d];
    const float* wp = &WnoT[d * DD + tid];
    a1 = fmaf(x.x, wp[0], a1);
    a1 = fmaf(x.y, wp[DD], a1);
    a1 = fmaf(x.z, wp[2 * DD], a1);
    a1 = fmaf(x.w, wp[3 * DD], a1);
  }
  a1 += nodes[(size_t)row * DD + tid];

  float x1;
  {
    float s = a1, ss = a1 * a1;
    #pragma unroll
    for (int off = 32; off > 0; off >>= 1) { s += __shfl_xor(s, off, 64); ss += __shfl_xor(ss, off, 64); }
    if ((tid & 63) == 0) { red[tid >> 6] = s; red[4 + (tid >> 6)] = ss; }
    __syncthreads();
    if (tid == 0) {
      const float S = red[0] + red[1] + red[2] + red[3];
      const float SS = red[4] + red[5] + red[6] + red[7];
      const float m = S * (1.f / 256.f);
      mv[0] = m; mv[1] = rsqrtf(SS * (1.f / 256.f) - m * m + 1e-5f);
    }
    __syncthreads();
    x1 = (a1 - mv[0]) * mv[1] * g1n[tid] + b1n[tid];
  }
  sX[tid] = x1;
  __syncthreads();

  float h1[4];
  #pragma unroll
  for (int p = 0; p < 4; ++p) h1[p] = bn1[p * 256 + tid];
  for (int d = 0; d < DD; d += 4) {
    const float4 x = *(const float4*)&sX[d];
    #pragma unroll
    for (int p = 0; p < 4; ++p) {
      const float* wp = &Wn1T[d * FF + p * 256 + tid];
      h1[p] = fmaf(x.x, wp[0], h1[p]);
      h1[p] = fmaf(x.y, wp[FF], h1[p]);
      h1[p] = fmaf(x.z, wp[2 * FF], h1[p]);
      h1[p] = fmaf(x.w, wp[3 * FF], h1[p]);
    }
  }
  #pragma unroll
  for (int p = 0; p < 4; ++p) sH[p * 256 + tid] = fmaxf(h1[p], 0.f);
  __syncthreads();

  float a2 = bn2[tid];
  for (int f = 0; f < FF; f += 4) {
    const float4 x = *(const float4*)&sH[f];
    const float* wp = &Wn2T[f * DD + tid];
    a2 = fmaf(x.x, wp[0], a2);
    a2 = fmaf(x.y, wp[DD], a2);
    a2 = fmaf(x.z, wp[2 * DD], a2);
    a2 = fmaf(x.w, wp[3 * DD], a2);
  }
  a2 += x1;

  {
    float s = a2, ss = a2 * a2;
    #pragma unroll
    for (int off = 32; off > 0; off >>= 1) { s += __shfl_xor(s, off, 64); ss += __shfl_xor(ss, off, 64); }
    if ((tid & 63) == 0) { red[tid >> 6] = s; red[4 + (tid >> 6)] = ss; }
    __syncthreads();
    if (tid == 0) {
      const float S = red[0] + red[1] + red[2] + red[3];
      const float SS = red[4] + red[5] + red[6] + red[7];
      const float m = S * (1.f / 256.f);
      mv[0] = m; mv[1] = rsqrtf(SS * (1.f / 256.f) - m * m + 1e-5f);
    }
    __syncthreads();
    out_nodes[(size_t)row * DD + tid] = (a2 - mv[0]) * mv[1] * g2n[tid] + b2n[tid];
  }
}

extern "C" void kernel_launch(void* const* d_in, const int* in_sizes, int n_in,
                              void* d_out, int out_size, void* d_ws, size_t ws_size,
                              hipStream_t stream) {
  const float* nodes = (const float*)d_in[0];
  const float* edges = (const float*)d_in[1];
  const float* conds = (const float*)d_in[2];
  const float* Wqkv = (const float*)d_in[3];
  const float* bqkv = (const float*)d_in[4];
  const float* Wno  = (const float*)d_in[5];
  const float* bno  = (const float*)d_in[6];
  const float* Weo  = (const float*)d_in[7];
  const float* beo  = (const float*)d_in[8];
  const float* g1n  = (const float*)d_in[9];
  const float* b1n  = (const float*)d_in[10];
  const float* g1e  = (const float*)d_in[11];
  const float* b1e  = (const float*)d_in[12];
  const float* Wn1  = (const float*)d_in[13];
  const float* bn1  = (const float*)d_in[14];
  const float* Wn2  = (const float*)d_in[15];
  const float* bn2  = (const float*)d_in[16];
  const float* We1  = (const float*)d_in[17];
  const float* be1  = (const float*)d_in[18];
  const float* We2  = (const float*)d_in[19];
  const float* be2  = (const float*)d_in[20];
  const float* g2n  = (const float*)d_in[21];
  const float* b2n  = (const float*)d_in[22];
  const float* g2e  = (const float*)d_in[23];
  const float* b2e  = (const float*)d_in[24];

  float* ws = (float*)d_ws;
  float* Q = ws;
  float* K = Q + BB * NNODE * DD;
  float* V = K + BB * NNODE * DD;
  float* logits = V + BB * NNODE * DD;                 // B*N*H*N
  float* WqkvT = logits + BB * NNODE * HH * NNODE;
  float* WnoT = WqkvT + 3 * DD * DD;
  float* Wn1T = WnoT + DD * DD;
  float* Wn2T = Wn1T + DD * FF;
  unsigned short* Weop = (unsigned short*)(Wn2T + FF * DD);
  unsigned short* We1p = Weop + EE * DD;
  unsigned short* We2p = We1p + FF * DD;

  float* out_nodes = (float*)d_out;
  float* out_edges = out_nodes + BB * NNODE * DD;
  float* out_conds = out_edges + (size_t)BB * NNODE * NNODE * EE;

  prep_kernel<<<3360, 256, 0, stream>>>(
      Wqkv, WqkvT, Wno, WnoT, Wn1, Wn1T, Wn2, Wn2T,
      Weo, Weop, We1, We1p, We2, We2p);

  qkv_kernel<<<BB * NNODE, 256, 0, stream>>>(nodes, conds, WqkvT, bqkv, Q, K, V);
  edge_mfma_kernel<<<BB * NNODE * (NNODE / 32), 256, 0, stream>>>(
      Q, K, edges, Weop, beo, g1e, b1e, We1p, be1, We2p, be2, g2e, b2e,
      logits, out_edges);
  softmax_kernel<<<BB * NNODE * HH, 64, 0, stream>>>(logits);
  node_kernel<<<BB * NNODE, 256, 0, stream>>>(
      logits, V, nodes, WnoT, bno, g1n, b1n, Wn1T, bn1, Wn2T, bn2, g2n, b2n,
      out_nodes);

  hipMemcpyAsync(out_conds, conds, BB * DD * sizeof(float),
                 hipMemcpyDeviceToDevice, stream);
}